// Round 1
// baseline (91.116 us; speedup 1.0000x reference)
//
#include <hip/hip_runtime.h>

typedef __attribute__((ext_vector_type(8))) short short8;
typedef __attribute__((ext_vector_type(4))) float f32x4;

#define TQ 64
#define TK 64
#define LDP 72      // padded LDS row stride (bf16 elems): breaks 16-way bank conflict
#define NTILE 16    // 1024 / 64

static __device__ __forceinline__ unsigned short f2bf(float f) {
  unsigned int u = __builtin_bit_cast(unsigned int, f);
  u = u + 0x7fffu + ((u >> 16) & 1u);   // round-to-nearest-even
  return (unsigned short)(u >> 16);
}

__global__ __launch_bounds__(256)
void dilated_attn(const float* __restrict__ Qg,
                  const float* __restrict__ Kg,
                  const float* __restrict__ Vg,
                  const int* __restrict__ causal_flag,
                  float* __restrict__ Og)
{
  __shared__ __align__(16) unsigned short K_lds[TK][LDP];
  __shared__ __align__(16) unsigned short Vt_lds[64][LDP];
  __shared__ __align__(16) unsigned short P_lds[4][16][LDP];

  const int tid  = threadIdx.x;
  const int wave = tid >> 6;
  const int lane = tid & 63;
  const int l15  = lane & 15;
  const int l4   = lane >> 4;

  const int qt   = blockIdx.x;
  const int inst = blockIdx.y;
  // group decode: insts [0,32) g0, [32,48) g1, [48,56) g2
  const int gi    = (inst < 32) ? 0 : ((inst < 48) ? 1 : 2);
  const int local = inst - ((gi == 0) ? 0 : ((gi == 1) ? 32 : 48));
  const int segs  = 4 >> gi;          // 4,2,1
  const int g     = 1024 << gi;       // 1024,2048,4096
  const int offs  = (gi == 0) ? 0 : ((gi == 1) ? 1 : 2);  // i % r
  const int h     = local & 3;
  const int rem   = local >> 2;       // b*segs + seg
  const int seg   = rem & (segs - 1);
  const int b     = rem >> (2 - gi);
  const int hh    = gi * 4 + h;

  const long base0  = ((long)(b * 4096 + seg * g + offs) * 12 + hh) * 64;
  const int  stride = (1 << gi) * 768;   // r * H * D elems between dilated tokens

  const int causal = *causal_flag;

  // ---- Q fragments in registers for the whole block (scale+log2e folded in) ----
  const float qscale = 0.125f * 1.44269504088896340736f;
  short8 a_q[2];
  {
    const int qrow = qt * TQ + wave * 16 + l15;
    const float* qp = Qg + base0 + (long)qrow * stride + l4 * 8;
#pragma unroll
    for (int ks = 0; ks < 2; ++ks) {
      float4 v0 = *(const float4*)(qp + ks * 32);
      float4 v1 = *(const float4*)(qp + ks * 32 + 4);
      short8 a;
      a[0] = (short)f2bf(v0.x * qscale); a[1] = (short)f2bf(v0.y * qscale);
      a[2] = (short)f2bf(v0.z * qscale); a[3] = (short)f2bf(v0.w * qscale);
      a[4] = (short)f2bf(v1.x * qscale); a[5] = (short)f2bf(v1.y * qscale);
      a[6] = (short)f2bf(v1.z * qscale); a[7] = (short)f2bf(v1.w * qscale);
      a_q[ks] = a;
    }
  }

  float m_run[4], l_run[4];
  f32x4 Oacc[4];
#pragma unroll
  for (int j = 0; j < 4; ++j) { m_run[j] = -INFINITY; l_run[j] = 0.f; }
#pragma unroll
  for (int n = 0; n < 4; ++n) Oacc[n] = (f32x4){0.f, 0.f, 0.f, 0.f};

  const int tt = tid >> 2;   // token within tile
  const int cb = tid & 3;    // 16-channel block
  const float* kbase = Kg + base0 + cb * 16;
  const float* vbase = Vg + base0 + cb * 16;

  for (int kt = 0; kt < NTILE; ++kt) {
    // ---- stage K (row-major) and V^T into LDS, fp32 -> bf16 ----
    {
      const long ro = (long)(kt * TK + tt) * stride;
      const float4 k0 = *(const float4*)(kbase + ro);
      const float4 k1 = *(const float4*)(kbase + ro + 4);
      const float4 k2 = *(const float4*)(kbase + ro + 8);
      const float4 k3 = *(const float4*)(kbase + ro + 12);
      const float4 w0 = *(const float4*)(vbase + ro);
      const float4 w1 = *(const float4*)(vbase + ro + 4);
      const float4 w2 = *(const float4*)(vbase + ro + 8);
      const float4 w3 = *(const float4*)(vbase + ro + 12);
      short8 ka, kb;
      ka[0]=(short)f2bf(k0.x); ka[1]=(short)f2bf(k0.y); ka[2]=(short)f2bf(k0.z); ka[3]=(short)f2bf(k0.w);
      ka[4]=(short)f2bf(k1.x); ka[5]=(short)f2bf(k1.y); ka[6]=(short)f2bf(k1.z); ka[7]=(short)f2bf(k1.w);
      kb[0]=(short)f2bf(k2.x); kb[1]=(short)f2bf(k2.y); kb[2]=(short)f2bf(k2.z); kb[3]=(short)f2bf(k2.w);
      kb[4]=(short)f2bf(k3.x); kb[5]=(short)f2bf(k3.y); kb[6]=(short)f2bf(k3.z); kb[7]=(short)f2bf(k3.w);
      *(short8*)&K_lds[tt][cb * 16]     = ka;
      *(short8*)&K_lds[tt][cb * 16 + 8] = kb;
      unsigned short vb[16];
      vb[0]=f2bf(w0.x);  vb[1]=f2bf(w0.y);  vb[2]=f2bf(w0.z);  vb[3]=f2bf(w0.w);
      vb[4]=f2bf(w1.x);  vb[5]=f2bf(w1.y);  vb[6]=f2bf(w1.z);  vb[7]=f2bf(w1.w);
      vb[8]=f2bf(w2.x);  vb[9]=f2bf(w2.y);  vb[10]=f2bf(w2.z); vb[11]=f2bf(w2.w);
      vb[12]=f2bf(w3.x); vb[13]=f2bf(w3.y); vb[14]=f2bf(w3.z); vb[15]=f2bf(w3.w);
#pragma unroll
      for (int i2 = 0; i2 < 16; ++i2) Vt_lds[cb * 16 + i2][tt] = vb[i2];
    }
    __syncthreads();

    // ---- S = Q K^T (one 16-row stripe per wave) ----
    f32x4 S[4];
#pragma unroll
    for (int n = 0; n < 4; ++n) {
      short8 b0 = *(const short8*)&K_lds[n * 16 + l15][l4 * 8];
      short8 b1 = *(const short8*)&K_lds[n * 16 + l15][32 + l4 * 8];
      f32x4 acc = (f32x4){0.f, 0.f, 0.f, 0.f};
      acc = __builtin_amdgcn_mfma_f32_16x16x32_bf16(a_q[0], b0, acc, 0, 0, 0);
      acc = __builtin_amdgcn_mfma_f32_16x16x32_bf16(a_q[1], b1, acc, 0, 0, 0);
      S[n] = acc;
    }

    if (causal) {
#pragma unroll
      for (int n = 0; n < 4; ++n)
#pragma unroll
        for (int j = 0; j < 4; ++j) {
          int kcol = kt * TK + n * 16 + l15;
          int qrow = qt * TQ + wave * 16 + l4 * 4 + j;
          if (kcol > qrow) S[n][j] = -INFINITY;
        }
    }

    // ---- online softmax (wave-parallel; rows live in 16-lane groups) ----
    float corr[4];
#pragma unroll
    for (int j = 0; j < 4; ++j) {
      float v = fmaxf(fmaxf(S[0][j], S[1][j]), fmaxf(S[2][j], S[3][j]));
      v = fmaxf(v, __shfl_xor(v, 1, 16));
      v = fmaxf(v, __shfl_xor(v, 2, 16));
      v = fmaxf(v, __shfl_xor(v, 4, 16));
      v = fmaxf(v, __shfl_xor(v, 8, 16));
      float mn = fmaxf(m_run[j], v);
      corr[j]  = exp2f(m_run[j] - mn);
      m_run[j] = mn;
    }
#pragma unroll
    for (int n = 0; n < 4; ++n)
#pragma unroll
      for (int j = 0; j < 4; ++j)
        S[n][j] = exp2f(S[n][j] - m_run[j]);
#pragma unroll
    for (int j = 0; j < 4; ++j) {
      float s = (S[0][j] + S[1][j]) + (S[2][j] + S[3][j]);
      s += __shfl_xor(s, 1, 16);
      s += __shfl_xor(s, 2, 16);
      s += __shfl_xor(s, 4, 16);
      s += __shfl_xor(s, 8, 16);
      l_run[j] = l_run[j] * corr[j] + s;
    }
#pragma unroll
    for (int n = 0; n < 4; ++n)
#pragma unroll
      for (int j = 0; j < 4; ++j)
        Oacc[n][j] *= corr[j];

    // ---- P (C-layout) -> LDS -> A-layout ----
#pragma unroll
    for (int n = 0; n < 4; ++n)
#pragma unroll
      for (int j = 0; j < 4; ++j)
        P_lds[wave][l4 * 4 + j][n * 16 + l15] = f2bf(S[n][j]);
    __syncthreads();

    // ---- O += P V ----
    {
      short8 ap0 = *(const short8*)&P_lds[wave][l15][l4 * 8];
      short8 ap1 = *(const short8*)&P_lds[wave][l15][32 + l4 * 8];
#pragma unroll
      for (int n = 0; n < 4; ++n) {
        short8 bv0 = *(const short8*)&Vt_lds[n * 16 + l15][l4 * 8];
        short8 bv1 = *(const short8*)&Vt_lds[n * 16 + l15][32 + l4 * 8];
        Oacc[n] = __builtin_amdgcn_mfma_f32_16x16x32_bf16(ap0, bv0, Oacc[n], 0, 0, 0);
        Oacc[n] = __builtin_amdgcn_mfma_f32_16x16x32_bf16(ap1, bv1, Oacc[n], 0, 0, 0);
      }
    }
    __syncthreads();
  }

  // ---- epilogue: O / l -> global (dilated scatter) ----
  float* ob = Og + base0;
#pragma unroll
  for (int j = 0; j < 4; ++j) {
    const float inv = 1.f / l_run[j];
    const int qrow = qt * TQ + wave * 16 + l4 * 4 + j;
    float* op = ob + (long)qrow * stride;
#pragma unroll
    for (int n = 0; n < 4; ++n)
      op[n * 16 + l15] = Oacc[n][j] * inv;
  }
}

extern "C" void kernel_launch(void* const* d_in, const int* in_sizes, int n_in,
                              void* d_out, int out_size, void* d_ws, size_t ws_size,
                              hipStream_t stream) {
  const float* Q = (const float*)d_in[0];
  const float* K = (const float*)d_in[1];
  const float* V = (const float*)d_in[2];
  const int* causal = (const int*)d_in[3];
  float* out = (float*)d_out;

  // zero output: dilated groups (r=2,4) leave uncovered positions = 0
  hipMemsetAsync(d_out, 0, (size_t)out_size * sizeof(float), stream);

  dim3 grid(NTILE, 56);   // 16 q-tiles x 56 attention instances
  dilated_attn<<<grid, 256, 0, stream>>>(Q, K, V, causal, out);
}

// Round 3
// 81.463 us; speedup vs baseline: 1.1185x; 1.1185x over previous
//
#include <hip/hip_runtime.h>
#include <hip/hip_bf16.h>

typedef __attribute__((ext_vector_type(8))) short short8;
typedef __attribute__((ext_vector_type(4))) float f32x4;

#define TQB 128     // q-rows per block (8 waves x 16)
#define TK 64       // kv tokens per tile
#define LDP 72      // padded LDS row stride (bf16 elems)
#define NTILE 16    // 1024 / 64

static __device__ __forceinline__ unsigned pk2(float x, float y) {
  // compiles to v_cvt_pk_bf16_f32 (RNE)
  __hip_bfloat162 h = __float22bfloat162_rn(make_float2(x, y));
  unsigned u;
  __builtin_memcpy(&u, &h, 4);
  return u;
}

static __device__ __forceinline__ short8 cvt8(float4 a, float4 b) {
  union { unsigned u[4]; short8 s; } r;
  r.u[0] = pk2(a.x, a.y); r.u[1] = pk2(a.z, a.w);
  r.u[2] = pk2(b.x, b.y); r.u[3] = pk2(b.z, b.w);
  return r.s;
}

__global__ __launch_bounds__(512)
void dilated_attn(const float* __restrict__ Qg,
                  const float* __restrict__ Kg,
                  const float* __restrict__ Vg,
                  const int* __restrict__ causal_flag,
                  float* __restrict__ Og)
{
  __shared__ __align__(16) unsigned short K_lds[TK][LDP];
  __shared__ __align__(16) unsigned short Vt_lds[64][LDP];
  __shared__ __align__(16) unsigned short P_lds[8][16][LDP];

  const int tid  = threadIdx.x;
  const int wave = tid >> 6;
  const int lane = tid & 63;
  const int l15  = lane & 15;
  const int l4   = lane >> 4;

  const int qt   = blockIdx.x;
  const int inst = blockIdx.y;
  // group decode: insts [0,32) g0, [32,48) g1, [48,56) g2
  const int gi    = (inst < 32) ? 0 : ((inst < 48) ? 1 : 2);
  const int local = inst - ((gi == 0) ? 0 : ((gi == 1) ? 32 : 48));
  const int segs  = 4 >> gi;          // 4,2,1
  const int g     = 1024 << gi;       // 1024,2048,4096
  const int offs  = (gi == 0) ? 0 : ((gi == 1) ? 1 : 2);  // i % r
  const int h     = local & 3;
  const int rem   = local >> 2;       // b*segs + seg
  const int seg   = rem & (segs - 1);
  const int b     = rem >> (2 - gi);
  const int hh    = gi * 4 + h;

  const long base0  = ((long)(b * 4096 + seg * g + offs) * 12 + hh) * 64;
  const int  stride = (1 << gi) * 768;   // r * H * D elems between dilated tokens

  const int causal = *causal_flag;

  // ---- Q fragments in registers (scale * log2e folded in) ----
  const float qscale = 0.125f * 1.44269504088896340736f;
  short8 a_q[2];
  {
    const int qrow = qt * TQB + wave * 16 + l15;
    const float* qp = Qg + base0 + (long)qrow * stride + l4 * 8;
#pragma unroll
    for (int ks = 0; ks < 2; ++ks) {
      float4 v0 = *(const float4*)(qp + ks * 32);
      float4 v1 = *(const float4*)(qp + ks * 32 + 4);
      v0.x *= qscale; v0.y *= qscale; v0.z *= qscale; v0.w *= qscale;
      v1.x *= qscale; v1.y *= qscale; v1.z *= qscale; v1.w *= qscale;
      a_q[ks] = cvt8(v0, v1);
    }
  }

  float m_run[4], l_run[4];
  f32x4 Oacc[4];
#pragma unroll
  for (int j = 0; j < 4; ++j) { m_run[j] = -INFINITY; l_run[j] = 0.f; }
#pragma unroll
  for (int n = 0; n < 4; ++n) Oacc[n] = (f32x4){0.f, 0.f, 0.f, 0.f};

  // staging mapping: 512 threads cover 64 tokens x 64 channels
  const int tt  = tid >> 3;   // token within tile (0..63)
  const int cb8 = tid & 7;    // 8-channel block
  const float* kbase = Kg + base0 + cb8 * 8;
  const float* vbase = Vg + base0 + cb8 * 8;

  for (int kt = 0; kt < NTILE; ++kt) {
    // ---- stage K (row-major) and V^T (XOR-swizzled) into LDS as bf16 ----
    {
      const long ro = (long)(kt * TK + tt) * stride;
      const float4 k0 = *(const float4*)(kbase + ro);
      const float4 k1 = *(const float4*)(kbase + ro + 4);
      const float4 w0 = *(const float4*)(vbase + ro);
      const float4 w1 = *(const float4*)(vbase + ro + 4);
      *(short8*)&K_lds[tt][cb8 * 8] = cvt8(k0, k1);
      // V^T: row d = cb8*8+i, col k = tt, col-block swizzled by ^(d>>3)=cb8
      unsigned p01 = pk2(w0.x, w0.y), p23 = pk2(w0.z, w0.w);
      unsigned p45 = pk2(w1.x, w1.y), p67 = pk2(w1.z, w1.w);
      const int col = (((tt >> 3) ^ cb8) << 3) | (tt & 7);
      Vt_lds[cb8 * 8 + 0][col] = (unsigned short)(p01 & 0xffff);
      Vt_lds[cb8 * 8 + 1][col] = (unsigned short)(p01 >> 16);
      Vt_lds[cb8 * 8 + 2][col] = (unsigned short)(p23 & 0xffff);
      Vt_lds[cb8 * 8 + 3][col] = (unsigned short)(p23 >> 16);
      Vt_lds[cb8 * 8 + 4][col] = (unsigned short)(p45 & 0xffff);
      Vt_lds[cb8 * 8 + 5][col] = (unsigned short)(p45 >> 16);
      Vt_lds[cb8 * 8 + 6][col] = (unsigned short)(p67 & 0xffff);
      Vt_lds[cb8 * 8 + 7][col] = (unsigned short)(p67 >> 16);
    }
    __syncthreads();

    // ---- S = Q K^T (one 16-row stripe per wave) ----
    f32x4 S[4];
#pragma unroll
    for (int n = 0; n < 4; ++n) {
      short8 b0 = *(const short8*)&K_lds[n * 16 + l15][l4 * 8];
      short8 b1 = *(const short8*)&K_lds[n * 16 + l15][32 + l4 * 8];
      f32x4 acc = (f32x4){0.f, 0.f, 0.f, 0.f};
      acc = __builtin_amdgcn_mfma_f32_16x16x32_bf16(a_q[0], b0, acc, 0, 0, 0);
      acc = __builtin_amdgcn_mfma_f32_16x16x32_bf16(a_q[1], b1, acc, 0, 0, 0);
      S[n] = acc;
    }

    if (causal) {
#pragma unroll
      for (int n = 0; n < 4; ++n)
#pragma unroll
        for (int j = 0; j < 4; ++j) {
          int kcol = kt * TK + n * 16 + l15;
          int qrow = qt * TQB + wave * 16 + l4 * 4 + j;
          if (kcol > qrow) S[n][j] = -INFINITY;
        }
    }

    // ---- online softmax (rows live in 16-lane groups) ----
    float corr[4];
#pragma unroll
    for (int j = 0; j < 4; ++j) {
      float v = fmaxf(fmaxf(S[0][j], S[1][j]), fmaxf(S[2][j], S[3][j]));
      v = fmaxf(v, __shfl_xor(v, 1, 16));
      v = fmaxf(v, __shfl_xor(v, 2, 16));
      v = fmaxf(v, __shfl_xor(v, 4, 16));
      v = fmaxf(v, __shfl_xor(v, 8, 16));
      float mn = fmaxf(m_run[j], v);
      corr[j]  = exp2f(m_run[j] - mn);
      m_run[j] = mn;
    }
#pragma unroll
    for (int n = 0; n < 4; ++n)
#pragma unroll
      for (int j = 0; j < 4; ++j)
        S[n][j] = exp2f(S[n][j] - m_run[j]);
#pragma unroll
    for (int j = 0; j < 4; ++j) {
      float s = (S[0][j] + S[1][j]) + (S[2][j] + S[3][j]);
      s += __shfl_xor(s, 1, 16);
      s += __shfl_xor(s, 2, 16);
      s += __shfl_xor(s, 4, 16);
      s += __shfl_xor(s, 8, 16);
      l_run[j] = l_run[j] * corr[j] + s;
    }
#pragma unroll
    for (int n = 0; n < 4; ++n)
#pragma unroll
      for (int j = 0; j < 4; ++j)
        Oacc[n][j] *= corr[j];

    // ---- P (C-layout) -> LDS -> A-layout ----
#pragma unroll
    for (int n = 0; n < 4; ++n) {
      unsigned plo = pk2(S[n][0], S[n][1]);
      unsigned phi = pk2(S[n][2], S[n][3]);
      P_lds[wave][l4 * 4 + 0][n * 16 + l15] = (unsigned short)(plo & 0xffff);
      P_lds[wave][l4 * 4 + 1][n * 16 + l15] = (unsigned short)(plo >> 16);
      P_lds[wave][l4 * 4 + 2][n * 16 + l15] = (unsigned short)(phi & 0xffff);
      P_lds[wave][l4 * 4 + 3][n * 16 + l15] = (unsigned short)(phi >> 16);
    }
    __syncthreads();

    // ---- O += P V (V^T reads un-swizzle the col-block) ----
    {
      short8 ap0 = *(const short8*)&P_lds[wave][l15][l4 * 8];
      short8 ap1 = *(const short8*)&P_lds[wave][l15][32 + l4 * 8];
#pragma unroll
      for (int n = 0; n < 4; ++n) {
        const int dsw = (2 * n + (l15 >> 3)) & 7;     // d>>3 for d = n*16+l15
        short8 bv0 = *(const short8*)&Vt_lds[n * 16 + l15][((l4 ^ dsw) & 7) * 8];
        short8 bv1 = *(const short8*)&Vt_lds[n * 16 + l15][(((4 + l4) ^ dsw) & 7) * 8];
        Oacc[n] = __builtin_amdgcn_mfma_f32_16x16x32_bf16(ap0, bv0, Oacc[n], 0, 0, 0);
        Oacc[n] = __builtin_amdgcn_mfma_f32_16x16x32_bf16(ap1, bv1, Oacc[n], 0, 0, 0);
      }
    }
    __syncthreads();
  }

  // ---- epilogue: O / l -> global (dilated scatter) ----
  float* ob = Og + base0;
#pragma unroll
  for (int j = 0; j < 4; ++j) {
    const float inv = 1.f / l_run[j];
    const int qrow = qt * TQB + wave * 16 + l4 * 4 + j;
    float* op = ob + (long)qrow * stride;
#pragma unroll
    for (int n = 0; n < 4; ++n)
      op[n * 16 + l15] = Oacc[n][j] * inv;
  }
}

extern "C" void kernel_launch(void* const* d_in, const int* in_sizes, int n_in,
                              void* d_out, int out_size, void* d_ws, size_t ws_size,
                              hipStream_t stream) {
  const float* Q = (const float*)d_in[0];
  const float* K = (const float*)d_in[1];
  const float* V = (const float*)d_in[2];
  const int* causal = (const int*)d_in[3];
  float* out = (float*)d_out;

  // zero output: dilated groups (r=2,4) leave uncovered positions = 0
  (void)hipMemsetAsync(d_out, 0, (size_t)out_size * sizeof(float), stream);

  dim3 grid(1024 / TQB, 56);   // 8 q-tiles x 56 attention instances
  dilated_attn<<<grid, 512, 0, stream>>>(Q, K, V, causal, out);
}

// Round 4
// 55.203 us; speedup vs baseline: 1.6506x; 1.4757x over previous
//
#include <hip/hip_runtime.h>
#include <hip/hip_bf16.h>

typedef __attribute__((ext_vector_type(8))) short short8;
typedef __attribute__((ext_vector_type(4))) float f32x4;

#define TQB 128     // q-rows per block (8 waves x 16)
#define TK 64       // kv tokens per tile
#define LDP 72      // padded LDS row stride (bf16 elems)
#define NTILE 16    // 1024 / 64

static __device__ __forceinline__ unsigned pk2(float x, float y) {
  // compiles to v_cvt_pk_bf16_f32 (RNE)
  __hip_bfloat162 h = __float22bfloat162_rn(make_float2(x, y));
  unsigned u;
  __builtin_memcpy(&u, &h, 4);
  return u;
}

static __device__ __forceinline__ short8 cvt8(float4 a, float4 b) {
  union { unsigned u[4]; short8 s; } r;
  r.u[0] = pk2(a.x, a.y); r.u[1] = pk2(a.z, a.w);
  r.u[2] = pk2(b.x, b.y); r.u[3] = pk2(b.z, b.w);
  return r.s;
}

__global__ __launch_bounds__(512, 4)
void dilated_attn(const float* __restrict__ Qg,
                  const float* __restrict__ Kg,
                  const float* __restrict__ Vg,
                  const int* __restrict__ causal_flag,
                  float* __restrict__ Og)
{
  // double-buffered K/V, per-wave-private P
  __shared__ __align__(16) unsigned short K_lds[2][TK][LDP];
  __shared__ __align__(16) unsigned short Vt_lds[2][64][LDP];
  __shared__ __align__(16) unsigned short P_lds[8][16][LDP];

  const int tid  = threadIdx.x;
  const int wave = tid >> 6;
  const int lane = tid & 63;
  const int l15  = lane & 15;
  const int l4   = lane >> 4;

  const int qt   = blockIdx.x;
  const int inst = blockIdx.y;
  const int gi    = (inst < 32) ? 0 : ((inst < 48) ? 1 : 2);
  const int local = inst - ((gi == 0) ? 0 : ((gi == 1) ? 32 : 48));
  const int segs  = 4 >> gi;
  const int g     = 1024 << gi;
  const int offs  = (gi == 0) ? 0 : ((gi == 1) ? 1 : 2);
  const int h     = local & 3;
  const int rem   = local >> 2;
  const int seg   = rem & (segs - 1);
  const int b     = rem >> (2 - gi);
  const int hh    = gi * 4 + h;

  const long base0  = ((long)(b * 4096 + seg * g + offs) * 12 + hh) * 64;
  const int  stride = (1 << gi) * 768;

  const int causal = *causal_flag;

  // ---- Q fragments (B operand of swapped QK^T); scale*log2e folded in ----
  const float qscale = 0.125f * 1.44269504088896340736f;
  short8 b_q[2];
  {
    const int qrow = qt * TQB + wave * 16 + l15;
    const float* qp = Qg + base0 + (long)qrow * stride + l4 * 8;
#pragma unroll
    for (int ks = 0; ks < 2; ++ks) {
      float4 v0 = *(const float4*)(qp + ks * 32);
      float4 v1 = *(const float4*)(qp + ks * 32 + 4);
      v0.x *= qscale; v0.y *= qscale; v0.z *= qscale; v0.w *= qscale;
      v1.x *= qscale; v1.y *= qscale; v1.z *= qscale; v1.w *= qscale;
      b_q[ks] = cvt8(v0, v1);
    }
  }

  // per-lane softmax state for q-row (qt*TQB + wave*16 + l15), replicated over l4
  float m_run = -INFINITY, l_run = 0.f;
  f32x4 Oacc[4];   // [n]: row q = l4*4+j, col d = n*16+l15
#pragma unroll
  for (int n = 0; n < 4; ++n) Oacc[n] = (f32x4){0.f, 0.f, 0.f, 0.f};

  // staging mapping: 512 threads cover 64 tokens x 64 channels
  const int tt  = tid >> 3;
  const int cb8 = tid & 7;
  const float* kbase = Kg + base0 + cb8 * 8;
  const float* vbase = Vg + base0 + cb8 * 8;

#define STAGE(BUF, A0, A1, W0, W1) do {                                        \
    *(short8*)&K_lds[BUF][tt][cb8 * 8] = cvt8(A0, A1);                         \
    unsigned p01 = pk2(W0.x, W0.y), p23 = pk2(W0.z, W0.w);                     \
    unsigned p45 = pk2(W1.x, W1.y), p67 = pk2(W1.z, W1.w);                     \
    const int col = (((tt >> 3) ^ cb8) << 3) | (tt & 7);                       \
    Vt_lds[BUF][cb8 * 8 + 0][col] = (unsigned short)(p01 & 0xffff);            \
    Vt_lds[BUF][cb8 * 8 + 1][col] = (unsigned short)(p01 >> 16);               \
    Vt_lds[BUF][cb8 * 8 + 2][col] = (unsigned short)(p23 & 0xffff);            \
    Vt_lds[BUF][cb8 * 8 + 3][col] = (unsigned short)(p23 >> 16);               \
    Vt_lds[BUF][cb8 * 8 + 4][col] = (unsigned short)(p45 & 0xffff);            \
    Vt_lds[BUF][cb8 * 8 + 5][col] = (unsigned short)(p45 >> 16);               \
    Vt_lds[BUF][cb8 * 8 + 6][col] = (unsigned short)(p67 & 0xffff);            \
    Vt_lds[BUF][cb8 * 8 + 7][col] = (unsigned short)(p67 >> 16);               \
  } while (0)

  // ---- prologue: stage tile 0 into buffer 0 ----
  {
    const long ro = (long)tt * stride;
    float4 k0 = *(const float4*)(kbase + ro);
    float4 k1 = *(const float4*)(kbase + ro + 4);
    float4 w0 = *(const float4*)(vbase + ro);
    float4 w1 = *(const float4*)(vbase + ro + 4);
    STAGE(0, k0, k1, w0, w1);
  }
  __syncthreads();

  const int qrow_me = qt * TQB + wave * 16 + l15;   // q-row this lane tracks

  for (int kt = 0; kt < NTILE; ++kt) {
    const int bsel = kt & 1;

    // ---- A: issue next tile's global loads (latency hides under compute) ----
    float4 nk0, nk1, nw0, nw1;
    const bool have_next = (kt + 1 < NTILE);
    if (have_next) {
      const long ro = (long)((kt + 1) * TK + tt) * stride;
      nk0 = *(const float4*)(kbase + ro);
      nk1 = *(const float4*)(kbase + ro + 4);
      nw0 = *(const float4*)(vbase + ro);
      nw1 = *(const float4*)(vbase + ro + 4);
    }

    // ---- B: S^T = K Q^T  (D row = k-token, col = q) ----
    f32x4 S[4];
#pragma unroll
    for (int n = 0; n < 4; ++n) {
      short8 ak0 = *(const short8*)&K_lds[bsel][n * 16 + l15][l4 * 8];
      short8 ak1 = *(const short8*)&K_lds[bsel][n * 16 + l15][32 + l4 * 8];
      f32x4 acc = (f32x4){0.f, 0.f, 0.f, 0.f};
      acc = __builtin_amdgcn_mfma_f32_16x16x32_bf16(ak0, b_q[0], acc, 0, 0, 0);
      acc = __builtin_amdgcn_mfma_f32_16x16x32_bf16(ak1, b_q[1], acc, 0, 0, 0);
      S[n] = acc;
    }

    if (causal) {
#pragma unroll
      for (int n = 0; n < 4; ++n)
#pragma unroll
        for (int j = 0; j < 4; ++j) {
          int ktok = kt * TK + n * 16 + l4 * 4 + j;
          if (ktok > qrow_me) S[n][j] = -INFINITY;
        }
    }

    // ---- online softmax: row is in-lane (16 vals) + 2-shfl reduce over l4 ----
    float pmax = S[0][0];
#pragma unroll
    for (int n = 0; n < 4; ++n)
#pragma unroll
      for (int j = 0; j < 4; ++j) pmax = fmaxf(pmax, S[n][j]);
    pmax = fmaxf(pmax, __shfl_xor(pmax, 16));
    pmax = fmaxf(pmax, __shfl_xor(pmax, 32));

    if (!__all(pmax - m_run <= 8.f)) {       // defer-max: rescale rarely
      float mn   = fmaxf(m_run, pmax);
      float corr = exp2f(m_run - mn);
      m_run = mn;
      l_run *= corr;
      float cq[4];
#pragma unroll
      for (int j = 0; j < 4; ++j) cq[j] = __shfl(corr, l4 * 4 + j, 16);
#pragma unroll
      for (int n = 0; n < 4; ++n)
#pragma unroll
        for (int j = 0; j < 4; ++j) Oacc[n][j] *= cq[j];
    }

    // P = exp2(S - m); per-lane partial row-sum (reduced once at epilogue)
    float psum = 0.f;
    unsigned up[4][2];
#pragma unroll
    for (int n = 0; n < 4; ++n)
#pragma unroll
      for (int hh2 = 0; hh2 < 2; ++hh2) {
        float p0 = exp2f(S[n][2 * hh2]     - m_run);
        float p1 = exp2f(S[n][2 * hh2 + 1] - m_run);
        psum += p0 + p1;
        up[n][hh2] = pk2(p0, p1);
      }
    l_run += psum;

    // ---- P (wave-private, no barrier): row q = l15, col k ----
#pragma unroll
    for (int n = 0; n < 4; ++n)
      *(uint2*)&P_lds[wave][l15][n * 16 + l4 * 4] = make_uint2(up[n][0], up[n][1]);

    // ---- O += P V ----
    {
      short8 ap0 = *(const short8*)&P_lds[wave][l15][l4 * 8];
      short8 ap1 = *(const short8*)&P_lds[wave][l15][32 + l4 * 8];
#pragma unroll
      for (int n = 0; n < 4; ++n) {
        const int dsw = (2 * n + (l15 >> 3)) & 7;
        short8 bv0 = *(const short8*)&Vt_lds[bsel][n * 16 + l15][((l4 ^ dsw) & 7) * 8];
        short8 bv1 = *(const short8*)&Vt_lds[bsel][n * 16 + l15][(((4 + l4) ^ dsw) & 7) * 8];
        Oacc[n] = __builtin_amdgcn_mfma_f32_16x16x32_bf16(ap0, bv0, Oacc[n], 0, 0, 0);
        Oacc[n] = __builtin_amdgcn_mfma_f32_16x16x32_bf16(ap1, bv1, Oacc[n], 0, 0, 0);
      }
    }

    // ---- C: write next tile into the other buffer, single barrier ----
    if (have_next) STAGE(bsel ^ 1, nk0, nk1, nw0, nw1);
    __syncthreads();
  }

  // ---- epilogue: finish l reduction, normalize, dilated scatter ----
  l_run += __shfl_xor(l_run, 16);
  l_run += __shfl_xor(l_run, 32);
  float lq[4];
#pragma unroll
  for (int j = 0; j < 4; ++j) lq[j] = __shfl(l_run, l4 * 4 + j, 16);

  float* ob = Og + base0;
#pragma unroll
  for (int j = 0; j < 4; ++j) {
    const float inv = 1.f / lq[j];
    const int qrow = qt * TQB + wave * 16 + l4 * 4 + j;
    float* op = ob + (long)qrow * stride;
#pragma unroll
    for (int n = 0; n < 4; ++n)
      op[n * 16 + l15] = Oacc[n][j] * inv;
  }
}

extern "C" void kernel_launch(void* const* d_in, const int* in_sizes, int n_in,
                              void* d_out, int out_size, void* d_ws, size_t ws_size,
                              hipStream_t stream) {
  const float* Q = (const float*)d_in[0];
  const float* K = (const float*)d_in[1];
  const float* V = (const float*)d_in[2];
  const int* causal = (const int*)d_in[3];
  float* out = (float*)d_out;

  // zero output: dilated groups (r=2,4) leave uncovered positions = 0
  (void)hipMemsetAsync(d_out, 0, (size_t)out_size * sizeof(float), stream);

  dim3 grid(1024 / TQB, 56);
  dilated_attn<<<grid, 512, 0, stream>>>(Q, K, V, causal, out);
}